// Round 1
// baseline (448.765 us; speedup 1.0000x reference)
//
#include <hip/hip_runtime.h>
#include <math.h>

#define DD 192
#define HH 192
#define WW 384
#define WV 575           // W + D - 1
#define TPIX 64          // pixels per tile
#define NG 16            // lane-groups per tile (4 pixels each)
#define NCHUNK 16        // d-chunks per block
#define DPC 12           // d values per chunk (16*12 = 192)

typedef float f4v __attribute__((ext_vector_type(4)));
typedef f4v unaligned_f4 __attribute__((aligned(4)));

__device__ __forceinline__ f4v ld4(const float* p) {
    return *reinterpret_cast<const unaligned_f4*>(p);
}

__device__ __forceinline__ f4v vmax(f4v a, f4v b) {
    f4v r;
    r.x = fmaxf(a.x, b.x); r.y = fmaxf(a.y, b.y);
    r.z = fmaxf(a.z, b.z); r.w = fmaxf(a.w, b.w);
    return r;
}

__device__ __forceinline__ f4v vexp(f4v a) {
    f4v r;
    r.x = __expf(a.x); r.y = __expf(a.y);
    r.z = __expf(a.z); r.w = __expf(a.w);
    return r;
}

__global__ __launch_bounds__(256, 3) void vr_kernel(const float* __restrict__ v,
                                                    float* __restrict__ out) {
    const int t = threadIdx.x;
    const int g = t & (NG - 1);        // lane-group: 4 consecutive pixels
    const int chunk = t >> 4;          // d-chunk 0..15
    const int tile = blockIdx.x;       // 0..1151
    const int h = tile / (WW / TPIX);
    const int w0 = (tile % (WW / TPIX)) * TPIX;
    const int w = w0 + g * 4;

    const size_t dstride = (size_t)HH * WV;       // 110400 floats per d-plane
    const size_t cstride = (size_t)DD * dstride;  // channel stride
    const float* base = v + (size_t)h * WV + (size_t)w;

    // online-softmax state, vectorized over this thread's 4 pixels
    f4v m1 = {-INFINITY, -INFINITY, -INFINITY, -INFINITY};
    f4v m2 = {-INFINITY, -INFINITY, -INFINITY, -INFINITY};
    f4v l1 = {0.f,0.f,0.f,0.f}, a1 = l1, c10 = l1, c11 = l1, c12 = l1;
    f4v l2 = l1, a2 = l1, c20 = l1, c21 = l1, c22 = l1;

    const int d0 = chunk * DPC;
    const float* p = base + (size_t)d0 * dstride;
    #pragma unroll 2
    for (int i = 0; i < DPC; ++i) {
        const int sh = (DD - 1) - (d0 + i);   // diagonal shift == disp value
        // 8 x 16B loads (pass1 aligned-window, pass2 diagonal; 4 channels)
        f4v b1  = ld4(p);
        f4v b2  = ld4(p + sh);
        f4v x10 = ld4(p + cstride);
        f4v x20 = ld4(p + cstride + sh);
        f4v x11 = ld4(p + 2 * cstride);
        f4v x21 = ld4(p + 2 * cstride + sh);
        f4v x12 = ld4(p + 3 * cstride);
        f4v x22 = ld4(p + 3 * cstride + sh);
        const float dv = (float)sh;

        // pass 1 online softmax update
        f4v nm = vmax(m1, b1);
        f4v s  = vexp(m1 - nm);
        f4v pr = vexp(b1 - nm);
        l1  = l1  * s + pr;
        a1  = a1  * s + pr * dv;
        c10 = c10 * s + pr * x10;
        c11 = c11 * s + pr * x11;
        c12 = c12 * s + pr * x12;
        m1 = nm;

        // pass 2 online softmax update
        nm = vmax(m2, b2);
        s  = vexp(m2 - nm);
        pr = vexp(b2 - nm);
        l2  = l2  * s + pr;
        a2  = a2  * s + pr * dv;
        c20 = c20 * s + pr * x20;
        c21 = c21 * s + pr * x21;
        c22 = c22 * s + pr * x22;
        m2 = nm;

        p += dstride;
    }

    // merge the 16 partial softmax states per pixel via LDS
    __shared__ float sm[NCHUNK][TPIX][12];
    #pragma unroll
    for (int j = 0; j < 4; ++j) {
        float* sp = sm[chunk][g * 4 + j];
        sp[0] = m1[j]; sp[1] = l1[j]; sp[2]  = a1[j];
        sp[3] = c10[j]; sp[4] = c11[j]; sp[5] = c12[j];
        sp[6] = m2[j]; sp[7] = l2[j]; sp[8]  = a2[j];
        sp[9] = c20[j]; sp[10] = c21[j]; sp[11] = c22[j];
    }
    __syncthreads();

    if (t < 2 * TPIX) {
        const int pix  = t & (TPIX - 1);
        const int pass = t >> 6;        // 0 = aligned, 1 = diagonal
        const int off  = pass * 6;
        float M = -INFINITY, L = 0.f, A = 0.f, C0 = 0.f, C1 = 0.f, C2 = 0.f;
        #pragma unroll
        for (int ch = 0; ch < NCHUNK; ++ch) {
            const float* q = sm[ch][pix] + off;
            float mm = q[0];
            float nm = fmaxf(M, mm);
            float s0 = __expf(M - nm);
            float s1 = __expf(mm - nm);
            L  = L  * s0 + q[1] * s1;
            A  = A  * s0 + q[2] * s1;
            C0 = C0 * s0 + q[3] * s1;
            C1 = C1 * s0 + q[4] * s1;
            C2 = C2 * s0 + q[5] * s1;
            M = nm;
        }
        const float inv = 1.0f / L;
        const int HW = HH * WW;
        const int o = h * WW + w0 + pix;
        // outputs flat-concatenated: color_1 (3HW), color_2 (3HW), disp_1 (HW), disp_2 (HW)
        out[(pass * 3 + 0) * HW + o] = C0 * inv;
        out[(pass * 3 + 1) * HW + o] = C1 * inv;
        out[(pass * 3 + 2) * HW + o] = C2 * inv;
        out[(6 + pass) * HW + o]     = A * inv;
    }
}

extern "C" void kernel_launch(void* const* d_in, const int* in_sizes, int n_in,
                              void* d_out, int out_size, void* d_ws, size_t ws_size,
                              hipStream_t stream) {
    const float* v = (const float*)d_in[0];
    float* out = (float*)d_out;
    const int grid = HH * (WW / TPIX);   // 1152 blocks, 256 threads
    vr_kernel<<<grid, 256, 0, stream>>>(v, out);
}